// Round 1
// baseline (1273.839 us; speedup 1.0000x reference)
//
#include <hip/hip_runtime.h>

namespace {

constexpr int Bsz = 16, Nsz = 2048, Esz = 1024, Gsz = 2, Vsz = 320, Dsz = 512;
constexpr int Msz = Bsz * Nsz;   // 32768 rows
constexpr int Fsz = Gsz * Vsz;   // 640 cols of W
constexpr int MT = 32;           // M tile per block
constexpr int KB = 32;           // K block

// Block: 256 threads. Computes h[m0:m0+32, g*320:(g+1)*320] fp32, then
// gumbel+argmax per row, gathers codebook row to out, histograms counts.
__global__ __launch_bounds__(256) void k_main(
    const float* __restrict__ x, const float* __restrict__ u,
    const float* __restrict__ W, const float* __restrict__ bias,
    const float* __restrict__ cb, float* __restrict__ out,
    int* __restrict__ counts) {
  __shared__ float xs[KB][MT + 4];   // [k][m], padded row (36 floats, 16B-aligned)
  __shared__ float wsh[KB][Vsz];     // [k][v]
  __shared__ int idx_sh[MT];

  const int m0 = blockIdx.x * MT;
  const int g = blockIdx.y;
  const int tid = threadIdx.x;
  const int trow = tid >> 5;   // 0..7  -> rows trow*4 .. trow*4+3
  const int tcol = tid & 31;   // 0..31 -> cols tcol*10 .. tcol*10+9

  float acc[4][10];
#pragma unroll
  for (int i = 0; i < 4; ++i)
#pragma unroll
    for (int j = 0; j < 10; ++j) acc[i][j] = 0.f;

  const int xr_row = tid >> 3;  // 0..31
  const int xr_kq = tid & 7;    // 0..7

  for (int k0 = 0; k0 < Esz; k0 += KB) {
    // stage loads in registers first (overlaps with previous compute drain)
    float4 xv = *(const float4*)(x + (size_t)(m0 + xr_row) * Esz + k0 + xr_kq * 4);
    float4 wv[10];
#pragma unroll
    for (int t = 0; t < 10; ++t) {
      int id = tid + 256 * t;        // 0..2559
      int k = id / 80;               // 0..31
      int vq = id % 80;              // 0..79 (float4 index)
      wv[t] = *(const float4*)(W + (size_t)(k0 + k) * Fsz + g * Vsz + vq * 4);
    }
    __syncthreads();  // previous tile's compute done
    xs[xr_kq * 4 + 0][xr_row] = xv.x;
    xs[xr_kq * 4 + 1][xr_row] = xv.y;
    xs[xr_kq * 4 + 2][xr_row] = xv.z;
    xs[xr_kq * 4 + 3][xr_row] = xv.w;
#pragma unroll
    for (int t = 0; t < 10; ++t) {
      int id = tid + 256 * t;
      int k = id / 80;
      int vq = id % 80;
      *(float4*)(&wsh[k][vq * 4]) = wv[t];
    }
    __syncthreads();
#pragma unroll 4
    for (int k = 0; k < KB; ++k) {
      float xr[4];
#pragma unroll
      for (int i = 0; i < 4; ++i) xr[i] = xs[k][trow * 4 + i];
      float wr[10];
#pragma unroll
      for (int j = 0; j < 10; ++j) wr[j] = wsh[k][tcol * 10 + j];
#pragma unroll
      for (int i = 0; i < 4; ++i)
#pragma unroll
        for (int j = 0; j < 10; ++j) acc[i][j] = fmaf(xr[i], wr[j], acc[i][j]);
    }
  }

  // ---- epilogue: bias + gumbel, per-row argmax over 320 ----
  const float C0 = 1.0f - 2.0f * 1e-7f;  // match reference fp32 constant
  float wb[10];
#pragma unroll
  for (int j = 0; j < 10; ++j) wb[j] = bias[g * Vsz + tcol * 10 + j];

#pragma unroll
  for (int i = 0; i < 4; ++i) {
    const int r = trow * 4 + i;
    const size_t m = (size_t)(m0 + r);
    const float* up = u + (m * Gsz + g) * (size_t)Vsz;
    float best = -3.4e38f;
    int bidx = Vsz;
#pragma unroll
    for (int j = 0; j < 10; ++j) {
      const int v = tcol * 10 + j;
      const float uu = up[v];
      // keep mul-then-add separate (NOT fma) to bitwise-match reference u'
      const float uprime = uu * C0 + 1e-7f;
      const float gn = -logf(-logf(uprime));
      const float z = acc[i][j] + wb[j] + gn;  // /TAU monotone -> skip
      if (z > best || (z == best && v < bidx)) { best = z; bidx = v; }
    }
    // reduce across the 32 lanes sharing this row (half-wave)
#pragma unroll
    for (int off = 16; off; off >>= 1) {
      const float ov = __shfl_xor(best, off, 32);
      const int oi = __shfl_xor(bidx, off, 32);
      if (ov > best || (ov == best && oi < bidx)) { best = ov; bidx = oi; }
    }
    if (tcol == 0) {
      idx_sh[r] = bidx;
      const int b = (int)(m / Nsz);
      atomicAdd(&counts[(b * Gsz + g) * Vsz + bidx], 1);
    }
  }
  __syncthreads();

  // ---- gather: out[m, g*512 + d] = cb[g, idx, d]; 32 rows x 128 float4 ----
#pragma unroll
  for (int t = 0; t < 16; ++t) {
    const int id = tid + 256 * t;  // 0..4095
    const int r = id >> 7;         // row 0..31
    const int dq = id & 127;       // float4 index within 512
    const int vidx = idx_sh[r];
    const float4 cv =
        *(const float4*)(cb + ((size_t)g * Vsz + vidx) * Dsz + dq * 4);
    *(float4*)(out + (size_t)(m0 + r) * (Gsz * Dsz) + g * Dsz + dq * 4) = cv;
  }
}

// one wave per (b,g): softmax over 320 counts, entropy partial
__global__ __launch_bounds__(64) void k_entropy(const int* __restrict__ counts,
                                                float* __restrict__ partial) {
  const int bg = blockIdx.x;  // 0..31
  const int lane = threadIdx.x;
  float c[5];
  float mx = -3.4e38f;
#pragma unroll
  for (int t = 0; t < 5; ++t) {
    c[t] = (float)counts[bg * Vsz + lane + 64 * t];
    mx = fmaxf(mx, c[t]);
  }
#pragma unroll
  for (int off = 32; off; off >>= 1) mx = fmaxf(mx, __shfl_xor(mx, off));
  float e[5];
  float s = 0.f;
#pragma unroll
  for (int t = 0; t < 5; ++t) {
    e[t] = expf(c[t] - mx);
    s += e[t];
  }
#pragma unroll
  for (int off = 32; off; off >>= 1) s += __shfl_xor(s, off);
  float ent = 0.f;
#pragma unroll
  for (int t = 0; t < 5; ++t) {
    const float p = e[t] / s;
    ent += p * logf(p + 1e-8f);
  }
#pragma unroll
  for (int off = 32; off; off >>= 1) ent += __shfl_xor(ent, off);
  if (lane == 0) partial[bg] = ent;
}

__global__ __launch_bounds__(64) void k_final(const float* __restrict__ partial,
                                              float* __restrict__ dst) {
  const int lane = threadIdx.x;
  float v = (lane < 32) ? partial[lane] : 0.f;
#pragma unroll
  for (int off = 32; off; off >>= 1) v += __shfl_xor(v, off);
  if (lane == 0) dst[0] = -v / (float)(Gsz * Vsz);
}

}  // namespace

extern "C" void kernel_launch(void* const* d_in, const int* in_sizes, int n_in,
                              void* d_out, int out_size, void* d_ws,
                              size_t ws_size, hipStream_t stream) {
  const float* x = (const float*)d_in[0];
  const float* u = (const float*)d_in[1];
  const float* W = (const float*)d_in[2];
  const float* bias = (const float*)d_in[3];
  const float* cb = (const float*)d_in[4];
  float* out = (float*)d_out;

  int* counts = (int*)d_ws;  // 32*320 ints
  float* partial = (float*)((char*)d_ws + (size_t)Bsz * Gsz * Vsz * 4);

  hipMemsetAsync(d_ws, 0, (size_t)Bsz * Gsz * Vsz * 4, stream);
  k_main<<<dim3(Msz / MT, Gsz), 256, 0, stream>>>(x, u, W, bias, cb, out,
                                                  counts);
  k_entropy<<<Bsz * Gsz, 64, 0, stream>>>(counts, partial);
  k_final<<<1, 64, 0, stream>>>(partial, out + (size_t)Msz * Esz);
}

// Round 2
// 1009.410 us; speedup vs baseline: 1.2620x; 1.2620x over previous
//
#include <hip/hip_runtime.h>

namespace {

constexpr int Bsz = 16, Nsz = 2048, Esz = 1024, Gsz = 2, Vsz = 320, Dsz = 512;
constexpr int Msz = Bsz * Nsz;   // 32768 rows
constexpr int Fsz = Gsz * Vsz;   // 640
constexpr int BM = 64;           // rows per block
constexpr int BK = 32;           // k per iteration

typedef __attribute__((ext_vector_type(8))) short bf16x8;
typedef __attribute__((ext_vector_type(4))) float f32x4;

__device__ __forceinline__ ushort f2bf(float f) {
  union { float f; unsigned u; } v; v.f = f;
  unsigned r = (v.u + 0x7FFFu + ((v.u >> 16) & 1u)) >> 16;  // RNE
  return (ushort)r;
}
__device__ __forceinline__ float bf2f(ushort h) {
  union { unsigned u; float f; } v; v.u = ((unsigned)h) << 16;
  return v.f;
}
__device__ __forceinline__ float gumb(float uu) {
  const float C0 = 1.0f - 2.0f * 1e-7f;
  float up = uu * C0 + 1e-7f;
  return -logf(-logf(up));
}

// ---- prep: split W (fp32 [k][f]) into bf16 hi/lo, transposed to [f][k] ----
__global__ __launch_bounds__(256) void k_prep(const float* __restrict__ W,
                                              ushort* __restrict__ wt_h,
                                              ushort* __restrict__ wt_l) {
  const int f = blockIdx.x;    // 0..639
  const int k0 = threadIdx.x * 4;
  float v[4];
#pragma unroll
  for (int i = 0; i < 4; ++i) v[i] = W[(size_t)(k0 + i) * Fsz + f];
  ushort4 hh, ll;
  hh.x = f2bf(v[0]); ll.x = f2bf(v[0] - bf2f(hh.x));
  hh.y = f2bf(v[1]); ll.y = f2bf(v[1] - bf2f(hh.y));
  hh.z = f2bf(v[2]); ll.z = f2bf(v[2] - bf2f(hh.z));
  hh.w = f2bf(v[3]); ll.w = f2bf(v[3] - bf2f(hh.w));
  *(ushort4*)(wt_h + (size_t)f * Esz + k0) = hh;
  *(ushort4*)(wt_l + (size_t)f * Esz + k0) = ll;
}

// ---- main: 64x320 tile per block, bf16x2 MFMA GEMM + fused epilogue ----
__global__ __launch_bounds__(640, 5) void k_main(
    const float* __restrict__ x, const float* __restrict__ u,
    const float* __restrict__ W, const float* __restrict__ bias,
    const float* __restrict__ cb, const ushort* __restrict__ wt_h,
    const ushort* __restrict__ wt_l, float* __restrict__ out,
    int* __restrict__ counts) {
  // LDS layout (ushort units): xs_h 64x40, xs_l 64x40, wsh_h 320x40, wsh_l 320x40
  // row stride 40 (pad 32->40: 80B, 2-way bank aliasing only). Total 60 KB.
  __shared__ __align__(16) ushort sm[30720];
  ushort* xs_h = sm;
  ushort* xs_l = sm + 2560;
  ushort* wsh_h = sm + 5120;
  ushort* wsh_l = sm + 17920;

  const int tid = threadIdx.x;
  const int m0 = blockIdx.x * BM;
  const int g = blockIdx.y;
  const int lane = tid & 63, w = tid >> 6;   // 10 waves
  const int wrow = w / 5, wcol = w - wrow * 5;
  const int lrow = lane & 15, quad = lane >> 4;

  f32x4 acc[2][4];
#pragma unroll
  for (int i = 0; i < 2; ++i)
#pragma unroll
    for (int j = 0; j < 4; ++j) acc[i][j] = (f32x4){0.f, 0.f, 0.f, 0.f};

  // loop-invariant LDS fragment offsets (A: m=lane&15, k=quad*8+j ; B: n=lane&15)
  int offA[2], offB[4];
#pragma unroll
  for (int rt = 0; rt < 2; ++rt)
    offA[rt] = (wrow * 32 + rt * 16 + lrow) * 40 + quad * 8;
#pragma unroll
  for (int ct = 0; ct < 4; ++ct)
    offB[ct] = (wcol * 64 + ct * 16 + lrow) * 40 + quad * 8;

  const int arow = tid >> 3, akq = tid & 7;  // A staging (tid<512)
  const ushort* wtg_h = wt_h + (size_t)g * Vsz * Esz;
  const ushort* wtg_l = wt_l + (size_t)g * Vsz * Esz;

  for (int k0 = 0; k0 < Esz; k0 += BK) {
    float4 xv;
    if (tid < 512)
      xv = *(const float4*)(x + (size_t)(m0 + arow) * Esz + k0 + akq * 4);
    uint4 br[4];
#pragma unroll
    for (int s = 0; s < 4; ++s) {
      int id = tid + 640 * s;             // 0..2559
      int plane = id / 1280;              // 0: hi, 1: lo
      int rem = id - plane * 1280;
      int n = rem >> 2, kq = rem & 3;
      const ushort* src = (plane ? wtg_l : wtg_h) + (size_t)n * Esz + k0 + kq * 8;
      br[s] = *(const uint4*)src;
    }
    __syncthreads();  // previous iteration's consumers done
    if (tid < 512) {
      ushort4 hh, ll;
      hh.x = f2bf(xv.x); ll.x = f2bf(xv.x - bf2f(hh.x));
      hh.y = f2bf(xv.y); ll.y = f2bf(xv.y - bf2f(hh.y));
      hh.z = f2bf(xv.z); ll.z = f2bf(xv.z - bf2f(hh.z));
      hh.w = f2bf(xv.w); ll.w = f2bf(xv.w - bf2f(hh.w));
      *(ushort4*)(xs_h + arow * 40 + akq * 4) = hh;
      *(ushort4*)(xs_l + arow * 40 + akq * 4) = ll;
    }
#pragma unroll
    for (int s = 0; s < 4; ++s) {
      int id = tid + 640 * s;
      int plane = id / 1280;
      int rem = id - plane * 1280;
      int n = rem >> 2, kq = rem & 3;
      ushort* dst = (plane ? wsh_l : wsh_h) + n * 40 + kq * 8;
      *(uint4*)dst = br[s];
    }
    __syncthreads();

    bf16x8 ah0 = *(const bf16x8*)(xs_h + offA[0]);
    bf16x8 ah1 = *(const bf16x8*)(xs_h + offA[1]);
    bf16x8 al0 = *(const bf16x8*)(xs_l + offA[0]);
    bf16x8 al1 = *(const bf16x8*)(xs_l + offA[1]);
#pragma unroll
    for (int ct = 0; ct < 4; ++ct) {
      bf16x8 bh = *(const bf16x8*)(wsh_h + offB[ct]);
      bf16x8 bl = *(const bf16x8*)(wsh_l + offB[ct]);
      acc[0][ct] = __builtin_amdgcn_mfma_f32_16x16x32_bf16(al0, bh, acc[0][ct], 0, 0, 0);
      acc[0][ct] = __builtin_amdgcn_mfma_f32_16x16x32_bf16(ah0, bl, acc[0][ct], 0, 0, 0);
      acc[0][ct] = __builtin_amdgcn_mfma_f32_16x16x32_bf16(ah0, bh, acc[0][ct], 0, 0, 0);
      acc[1][ct] = __builtin_amdgcn_mfma_f32_16x16x32_bf16(al1, bh, acc[1][ct], 0, 0, 0);
      acc[1][ct] = __builtin_amdgcn_mfma_f32_16x16x32_bf16(ah1, bl, acc[1][ct], 0, 0, 0);
      acc[1][ct] = __builtin_amdgcn_mfma_f32_16x16x32_bf16(ah1, bh, acc[1][ct], 0, 0, 0);
    }
  }

  // ---- epilogue: z = h + bias + gumbel; per-row top-2 ----
  __syncthreads();  // LDS tiles free; reuse for reduction buffers
  float4* red = (float4*)sm;           // [64][5] (v1, i1, v2, i2)
  int* idx_sh = (int*)(sm + 2560);     // [64]

  const float* bptr = bias + g * Vsz;
#pragma unroll
  for (int rt = 0; rt < 2; ++rt) {
#pragma unroll
    for (int rg = 0; rg < 4; ++rg) {
      const int row = wrow * 32 + rt * 16 + quad * 4 + rg;  // C/D: row=quad*4+reg
      const size_t m = (size_t)(m0 + row);
      const float* up = u + (m * Gsz + g) * Vsz;
      float v1 = -3.4e38f, v2 = -3.4e38f;
      int i1 = 1 << 30, i2 = 1 << 30;
#pragma unroll
      for (int ct = 0; ct < 4; ++ct) {
        const int c = wcol * 64 + ct * 16 + lrow;  // C/D: col=lane&15
        const float z = acc[rt][ct][rg] + bptr[c] + gumb(up[c]);
        if (z > v1 || (z == v1 && c < i1)) {
          v2 = v1; i2 = i1; v1 = z; i1 = c;
        } else if (z > v2 || (z == v2 && c < i2)) {
          v2 = z; i2 = c;
        }
      }
#pragma unroll
      for (int off = 1; off < 16; off <<= 1) {
        float ov1 = __shfl_xor(v1, off, 16); int oi1 = __shfl_xor(i1, off, 16);
        float ov2 = __shfl_xor(v2, off, 16); int oi2 = __shfl_xor(i2, off, 16);
        const bool owins = (ov1 > v1) || (ov1 == v1 && oi1 < i1);
        if (owins) {
          const bool keep = (v1 > ov2) || (v1 == ov2 && i1 < oi2);
          v2 = keep ? v1 : ov2; i2 = keep ? i1 : oi2;
          v1 = ov1; i1 = oi1;
        } else if ((ov1 > v2) || (ov1 == v2 && oi1 < i2)) {
          v2 = ov1; i2 = oi1;
        }
      }
      if (lrow == 0) {
        float4 t;
        t.x = v1; t.y = __int_as_float(i1);
        t.z = v2; t.w = __int_as_float(i2);
        red[row * 5 + wcol] = t;
      }
    }
  }
  __syncthreads();

  if (tid < 64) {
    const int r = tid;
    const size_t m = (size_t)(m0 + r);
    float v1 = -3.4e38f, v2 = -3.4e38f;
    int i1 = 1 << 30, i2 = 1 << 30;
#pragma unroll
    for (int wc = 0; wc < 5; ++wc) {
      const float4 t = red[r * 5 + wc];
      const float ov1 = t.x, ov2 = t.z;
      const int oi1 = __float_as_int(t.y), oi2 = __float_as_int(t.w);
      const bool owins = (ov1 > v1) || (ov1 == v1 && oi1 < i1);
      if (owins) {
        const bool keep = (v1 > ov2) || (v1 == ov2 && i1 < oi2);
        v2 = keep ? v1 : ov2; i2 = keep ? i1 : oi2;
        v1 = ov1; i1 = oi1;
      } else if ((ov1 > v2) || (ov1 == v2 && oi1 < i2)) {
        v2 = ov1; i2 = oi1;
      }
    }
    // near-tie: re-decide the two candidates with exact fp32 dot products
    if (v1 - v2 < 1e-3f) {
      const float* xp = x + m * Esz;
      const float* wp = W + g * Vsz;
      float h1 = 0.f, h2 = 0.f;
      for (int k = 0; k < Esz; ++k) {
        const float xvv = xp[k];
        h1 = fmaf(xvv, wp[(size_t)k * Fsz + i1], h1);
        h2 = fmaf(xvv, wp[(size_t)k * Fsz + i2], h2);
      }
      const float* up = u + (m * Gsz + g) * Vsz;
      const float z1 = h1 + bptr[i1] + gumb(up[i1]);
      const float z2 = h2 + bptr[i2] + gumb(up[i2]);
      if ((z2 > z1) || (z2 == z1 && i2 < i1)) i1 = i2;
    }
    idx_sh[r] = i1;
    const int b = (int)(m >> 11);  // N=2048
    atomicAdd(&counts[(b * Gsz + g) * Vsz + i1], 1);
  }
  __syncthreads();

  // ---- gather codebook rows to out ----
  for (int id = tid; id < BM * 128; id += 640) {
    const int r = id >> 7, dq = id & 127;
    const int vidx = idx_sh[r];
    const float4 cv =
        *(const float4*)(cb + ((size_t)g * Vsz + vidx) * Dsz + dq * 4);
    *(float4*)(out + (size_t)(m0 + r) * (Gsz * Dsz) + g * Dsz + dq * 4) = cv;
  }
}

// ---- entropy over histogram ----
__global__ __launch_bounds__(64) void k_entropy(const int* __restrict__ counts,
                                                float* __restrict__ partial) {
  const int bg = blockIdx.x;
  const int lane = threadIdx.x;
  float c[5];
  float mx = -3.4e38f;
#pragma unroll
  for (int t = 0; t < 5; ++t) {
    c[t] = (float)counts[bg * Vsz + lane + 64 * t];
    mx = fmaxf(mx, c[t]);
  }
#pragma unroll
  for (int off = 32; off; off >>= 1) mx = fmaxf(mx, __shfl_xor(mx, off));
  float e[5];
  float s = 0.f;
#pragma unroll
  for (int t = 0; t < 5; ++t) {
    e[t] = expf(c[t] - mx);
    s += e[t];
  }
#pragma unroll
  for (int off = 32; off; off >>= 1) s += __shfl_xor(s, off);
  float ent = 0.f;
#pragma unroll
  for (int t = 0; t < 5; ++t) {
    const float p = e[t] / s;
    ent += p * logf(p + 1e-8f);
  }
#pragma unroll
  for (int off = 32; off; off >>= 1) ent += __shfl_xor(ent, off);
  if (lane == 0) partial[bg] = ent;
}

__global__ __launch_bounds__(64) void k_final(const float* __restrict__ partial,
                                              float* __restrict__ dst) {
  const int lane = threadIdx.x;
  float v = (lane < 32) ? partial[lane] : 0.f;
#pragma unroll
  for (int off = 32; off; off >>= 1) v += __shfl_xor(v, off);
  if (lane == 0) dst[0] = -v / (float)(Gsz * Vsz);
}

}  // namespace

extern "C" void kernel_launch(void* const* d_in, const int* in_sizes, int n_in,
                              void* d_out, int out_size, void* d_ws,
                              size_t ws_size, hipStream_t stream) {
  const float* x = (const float*)d_in[0];
  const float* u = (const float*)d_in[1];
  const float* W = (const float*)d_in[2];
  const float* bias = (const float*)d_in[3];
  const float* cb = (const float*)d_in[4];
  float* out = (float*)d_out;

  // workspace: [0,40960) counts ; [40960,41088) partial ; [65536,...) wt h/l
  int* counts = (int*)d_ws;
  float* partial = (float*)((char*)d_ws + 40960);
  ushort* wt_h = (ushort*)((char*)d_ws + 65536);
  ushort* wt_l = wt_h + (size_t)Fsz * Esz;

  hipMemsetAsync(d_ws, 0, 40960, stream);
  k_prep<<<Fsz, 256, 0, stream>>>(W, wt_h, wt_l);
  k_main<<<dim3(Msz / BM, Gsz), 640, 0, stream>>>(x, u, W, bias, cb, wt_h,
                                                  wt_l, out, counts);
  k_entropy<<<Bsz * Gsz, 64, 0, stream>>>(counts, partial);
  k_final<<<1, 64, 0, stream>>>(partial, out + (size_t)Msz * Esz);
}

// Round 3
// 712.151 us; speedup vs baseline: 1.7887x; 1.4174x over previous
//
#include <hip/hip_runtime.h>

namespace {

constexpr int Bsz = 16, Nsz = 2048, Esz = 1024, Gsz = 2, Vsz = 320, Dsz = 512;
constexpr int Msz = Bsz * Nsz;   // 32768 rows
constexpr int Fsz = Gsz * Vsz;   // 640
constexpr int BM = 128, BN = 128, BK = 32;

typedef __attribute__((ext_vector_type(8))) short bf16x8;
typedef __attribute__((ext_vector_type(4))) float f32x4;
typedef unsigned int u32;
typedef unsigned short u16;

__device__ __forceinline__ void load_lds16(const void* g, void* l) {
  __builtin_amdgcn_global_load_lds(
      (const __attribute__((address_space(1))) u32*)g,
      (__attribute__((address_space(3))) u32*)l, 16, 0, 0);
}

__device__ __forceinline__ ushort f2bf(float f) {
  union { float f; unsigned u; } v; v.f = f;
  unsigned r = (v.u + 0x7FFFu + ((v.u >> 16) & 1u)) >> 16;  // RNE
  return (ushort)r;
}
__device__ __forceinline__ float bf2f(ushort h) {
  union { unsigned u; float f; } v; v.u = ((unsigned)h) << 16;
  return v.f;
}

// precise gumbel (matches rounds 1/2 which scored absmax 0)
__device__ __forceinline__ float gumb_precise(float uu) {
  const float C0 = 1.0f - 2.0f * 1e-7f;
  float up = uu * C0;
  up = up + 1e-7f;
  return -logf(-logf(up));
}
// fast gumbel for candidate SELECTION only (abs err <~2e-5, threshold 1e-3):
// inner log via 5-term series when up>=0.84 (v_log abs-error amplification
// zone), hw log elsewhere; outer always hw log.
__device__ __forceinline__ float gumb_fast(float uu) {
  const float C0 = 1.0f - 2.0f * 1e-7f;
  const float up = fmaf(uu, C0, 1e-7f);
  const float d = 1.0f - up;  // exact for up>=0.5 (Sterbenz)
  const float ypoly =
      d * fmaf(d, fmaf(d, fmaf(d, fmaf(d, 0.2f, 0.25f), 0.33333334f), 0.5f), 1.0f);
  const float yfast = -__logf(up);
  const float y = (up >= 0.84f) ? ypoly : yfast;
  return -__logf(y);
}

struct Top2 { float v1, v2; int i1, i2; };
__device__ __forceinline__ void t2_feed(Top2& t, float z, int f) {
  if (z > t.v1 || (z == t.v1 && f < t.i1)) {
    t.v2 = t.v1; t.i2 = t.i1; t.v1 = z; t.i1 = f;
  } else if (z > t.v2 || (z == t.v2 && f < t.i2)) {
    t.v2 = z; t.i2 = f;
  }
}
__device__ __forceinline__ void t2_merge(Top2& t, float ov1, int oi1, float ov2,
                                         int oi2) {
  if (ov1 > t.v1 || (ov1 == t.v1 && oi1 < t.i1)) {
    const bool keep = (t.v1 > ov2) || (t.v1 == ov2 && t.i1 < oi2);
    t.v2 = keep ? t.v1 : ov2; t.i2 = keep ? t.i1 : oi2;
    t.v1 = ov1; t.i1 = oi1;
  } else if (ov1 > t.v2 || (ov1 == t.v2 && oi1 < t.i2)) {
    t.v2 = ov1; t.i2 = oi1;
  }
}

// ---- prep: split W (fp32 [k][f]) into bf16 hi/lo, transposed to [f][k] ----
__global__ __launch_bounds__(256) void k_prep(const float* __restrict__ W,
                                              u16* __restrict__ wt_h,
                                              u16* __restrict__ wt_l) {
  const int f = blockIdx.x;    // 0..639
  const int k0 = threadIdx.x * 4;
  float v[4];
#pragma unroll
  for (int i = 0; i < 4; ++i) v[i] = W[(size_t)(k0 + i) * Fsz + f];
  ushort4 hh, ll;
  hh.x = f2bf(v[0]); ll.x = f2bf(v[0] - bf2f(hh.x));
  hh.y = f2bf(v[1]); ll.y = f2bf(v[1] - bf2f(hh.y));
  hh.z = f2bf(v[2]); ll.z = f2bf(v[2] - bf2f(hh.z));
  hh.w = f2bf(v[3]); ll.w = f2bf(v[3] - bf2f(hh.w));
  *(ushort4*)(wt_h + (size_t)f * Esz + k0) = hh;
  *(ushort4*)(wt_l + (size_t)f * Esz + k0) = ll;
}

// ---- GEMM: m97 structure. 128x128 tile, 4 waves 2x2, BK=32, 3-term bf16x2.
// Epilogue: gumbel + per-row top-2 over each wave's 64 cols -> partials.
__global__ __launch_bounds__(256) void k_gemm(
    const float* __restrict__ x, const float* __restrict__ u,
    const float* __restrict__ bias, const u16* __restrict__ wth,
    const u16* __restrict__ wtl, float4* __restrict__ partial) {
  __shared__ __align__(16) u16 sm[16384];  // 32 KB
  u16* xs_h = sm;            // 128x32
  u16* xs_l = sm + 4096;
  u16* bs_h = sm + 8192;     // 128x32 (local cols)
  u16* bs_l = sm + 12288;

  const int tid = threadIdx.x;
  const int n0 = blockIdx.x * BN;   // n-tile fastest -> x-tile L2 reuse
  const int m0 = blockIdx.y * BM;
  const int lane = tid & 63, w = tid >> 6;
  const int wr = w >> 1, wc = w & 1;
  const int lrow = lane & 15, quad = lane >> 4;

  f32x4 acc[4][4];
#pragma unroll
  for (int i = 0; i < 4; ++i)
#pragma unroll
    for (int j = 0; j < 4; ++j) acc[i][j] = (f32x4){0.f, 0.f, 0.f, 0.f};

  for (int k0 = 0; k0 < Esz; k0 += BK) {
    // A fp32 tile loads into regs (before barrier: overlaps prev compute)
    float4 av[4];
#pragma unroll
    for (int s = 0; s < 4; ++s) {
      const int id = tid + 256 * s;       // 0..1023
      const int row = id >> 3, kq = id & 7;
      av[s] = *(const float4*)(x + (size_t)(m0 + row) * Esz + k0 + kq * 4);
    }
    __syncthreads();  // prev iteration's LDS consumers done
    // B planes via global->LDS DMA, 16 chunks of 1024B, 4 per wave
#pragma unroll
    for (int c = 0; c < 4; ++c) {
      const int chunk = w + 4 * c;        // wave-uniform
      const int plane = chunk >> 3, ch = chunk & 7;
      const u16* src = (plane ? wtl : wth) +
                       (size_t)(n0 + ch * 16 + (lane >> 2)) * Esz + k0 +
                       (lane & 3) * 8;
      u16* dst = (plane ? bs_l : bs_h) + ch * 512;
      load_lds16(src, dst);
    }
    // A truncation split: xh = trunc16(x) (exact residual), xl = trunc16(x-xh)
#pragma unroll
    for (int s = 0; s < 4; ++s) {
      const int id = tid + 256 * s;
      const int row = id >> 3, kq = id & 7;
      const u32 u0 = __float_as_uint(av[s].x), u1 = __float_as_uint(av[s].y);
      const u32 u2 = __float_as_uint(av[s].z), u3 = __float_as_uint(av[s].w);
      uint2 hh, ll;
      hh.x = (u0 >> 16) | (u1 & 0xffff0000u);
      hh.y = (u2 >> 16) | (u3 & 0xffff0000u);
      const float r0 = av[s].x - __uint_as_float(u0 & 0xffff0000u);
      const float r1 = av[s].y - __uint_as_float(u1 & 0xffff0000u);
      const float r2 = av[s].z - __uint_as_float(u2 & 0xffff0000u);
      const float r3 = av[s].w - __uint_as_float(u3 & 0xffff0000u);
      ll.x = (__float_as_uint(r0) >> 16) | (__float_as_uint(r1) & 0xffff0000u);
      ll.y = (__float_as_uint(r2) >> 16) | (__float_as_uint(r3) & 0xffff0000u);
      *(uint2*)(xs_h + row * 32 + kq * 4) = hh;
      *(uint2*)(xs_l + row * 32 + kq * 4) = ll;
    }
    __syncthreads();  // drains vmcnt (B DMA) + lgkm (A writes)

    bf16x8 ah[4], al[4];
#pragma unroll
    for (int rt = 0; rt < 4; ++rt) {
      const int off = (wr * 64 + rt * 16 + lrow) * 32 + quad * 8;
      ah[rt] = *(const bf16x8*)(xs_h + off);
      al[rt] = *(const bf16x8*)(xs_l + off);
    }
#pragma unroll
    for (int ct = 0; ct < 4; ++ct) {
      const int off = (wc * 64 + ct * 16 + lrow) * 32 + quad * 8;
      const bf16x8 bh = *(const bf16x8*)(bs_h + off);
      const bf16x8 bl = *(const bf16x8*)(bs_l + off);
#pragma unroll
      for (int rt = 0; rt < 4; ++rt) {
        acc[rt][ct] = __builtin_amdgcn_mfma_f32_16x16x32_bf16(al[rt], bh, acc[rt][ct], 0, 0, 0);
        acc[rt][ct] = __builtin_amdgcn_mfma_f32_16x16x32_bf16(ah[rt], bl, acc[rt][ct], 0, 0, 0);
        acc[rt][ct] = __builtin_amdgcn_mfma_f32_16x16x32_bf16(ah[rt], bh, acc[rt][ct], 0, 0, 0);
      }
    }
  }

  // ---- epilogue: z = h + bias + gumbel ; per-row top-2 over wave's 64 cols
  const int pcol = blockIdx.x * 2 + wc;  // 64-col block id, 0..9
#pragma unroll
  for (int rt = 0; rt < 4; ++rt) {
#pragma unroll
    for (int rg = 0; rg < 4; ++rg) {
      const int row = wr * 64 + rt * 16 + quad * 4 + rg;  // C/D row=quad*4+reg
      const size_t m = (size_t)(m0 + row);
      Top2 t; t.v1 = -3.4e38f; t.v2 = -3.4e38f; t.i1 = 1 << 30; t.i2 = 1 << 30;
#pragma unroll
      for (int ct = 0; ct < 4; ++ct) {
        const int f = n0 + wc * 64 + ct * 16 + lrow;      // C/D col=lane&15
        const float z = acc[rt][ct][rg] + bias[f] + gumb_fast(u[m * 640 + f]);
        t2_feed(t, z, f);
      }
#pragma unroll
      for (int off = 1; off < 16; off <<= 1) {
        const float ov1 = __shfl_xor(t.v1, off, 16);
        const int oi1 = __shfl_xor(t.i1, off, 16);
        const float ov2 = __shfl_xor(t.v2, off, 16);
        const int oi2 = __shfl_xor(t.i2, off, 16);
        t2_merge(t, ov1, oi1, ov2, oi2);
      }
      if (lrow == 0) {
        float4 o;
        o.x = t.v1; o.y = __int_as_float(t.i1);
        o.z = t.v2; o.w = __int_as_float(t.i2);
        partial[m * 10 + pcol] = o;
      }
    }
  }
}

// ---- select: merge partials per group, exact recheck near ties, gather ----
__global__ __launch_bounds__(256) void k_select(
    const float4* __restrict__ partial, const float* __restrict__ x,
    const float* __restrict__ W, const float* __restrict__ bias,
    const float* __restrict__ u, const float* __restrict__ cb,
    float* __restrict__ out, int* __restrict__ counts) {
  __shared__ int idx_sh[256][2];
  const int tid = threadIdx.x;
  const size_t m = (size_t)blockIdx.x * 256 + tid;

#pragma unroll
  for (int g = 0; g < 2; ++g) {
    Top2 t; t.v1 = -3.4e38f; t.v2 = -3.4e38f; t.i1 = 1 << 30; t.i2 = 1 << 30;
#pragma unroll
    for (int p = 0; p < 5; ++p) {
      const float4 q = partial[m * 10 + g * 5 + p];
      t2_merge(t, q.x, __float_as_int(q.y), q.z, __float_as_int(q.w));
    }
    int i1 = t.i1;
    if (t.v1 - t.v2 < 1e-3f) {  // near tie: exact fp32 recheck of both
      const int i2 = t.i2;
      const float* xp = x + m * Esz;
      float h1 = 0.f, h2 = 0.f;
      for (int k = 0; k < Esz; ++k) {
        const float xv = xp[k];
        h1 = fmaf(xv, W[(size_t)k * Fsz + i1], h1);
        h2 = fmaf(xv, W[(size_t)k * Fsz + i2], h2);
      }
      const float z1 = h1 + bias[i1] + gumb_precise(u[m * 640 + i1]);
      const float z2 = h2 + bias[i2] + gumb_precise(u[m * 640 + i2]);
      if (z2 > z1 || (z2 == z1 && i2 < i1)) i1 = i2;
    }
    const int v = i1 - g * Vsz;
    idx_sh[tid][g] = v;
    const int b = (int)(m >> 11);  // N=2048
    atomicAdd(&counts[(b * Gsz + g) * Vsz + v], 1);
  }
  __syncthreads();

  // gather: one row per iteration, 256 threads = 1024 floats, coalesced
  const size_t mbase = (size_t)blockIdx.x * 256;
  const int gq = tid >> 7, dq = tid & 127;
  for (int it = 0; it < 256; ++it) {
    const int v = idx_sh[it][gq];
    const float4 cv =
        *(const float4*)(cb + ((size_t)(gq * Vsz + v)) * Dsz + dq * 4);
    *(float4*)(out + (mbase + it) * (size_t)(Gsz * Dsz) + tid * 4) = cv;
  }
}

// ---- entropy over histogram ----
__global__ __launch_bounds__(64) void k_entropy(const int* __restrict__ counts,
                                                float* __restrict__ partial) {
  const int bg = blockIdx.x;
  const int lane = threadIdx.x;
  float c[5];
  float mx = -3.4e38f;
#pragma unroll
  for (int t = 0; t < 5; ++t) {
    c[t] = (float)counts[bg * Vsz + lane + 64 * t];
    mx = fmaxf(mx, c[t]);
  }
#pragma unroll
  for (int off = 32; off; off >>= 1) mx = fmaxf(mx, __shfl_xor(mx, off));
  float e[5];
  float s = 0.f;
#pragma unroll
  for (int t = 0; t < 5; ++t) {
    e[t] = expf(c[t] - mx);
    s += e[t];
  }
#pragma unroll
  for (int off = 32; off; off >>= 1) s += __shfl_xor(s, off);
  float ent = 0.f;
#pragma unroll
  for (int t = 0; t < 5; ++t) {
    const float p = e[t] / s;
    ent += p * logf(p + 1e-8f);
  }
#pragma unroll
  for (int off = 32; off; off >>= 1) ent += __shfl_xor(ent, off);
  if (lane == 0) partial[bg] = ent;
}

__global__ __launch_bounds__(64) void k_final(const float* __restrict__ partial,
                                              float* __restrict__ dst) {
  const int lane = threadIdx.x;
  float v = (lane < 32) ? partial[lane] : 0.f;
#pragma unroll
  for (int off = 32; off; off >>= 1) v += __shfl_xor(v, off);
  if (lane == 0) dst[0] = -v / (float)(Gsz * Vsz);
}

}  // namespace

extern "C" void kernel_launch(void* const* d_in, const int* in_sizes, int n_in,
                              void* d_out, int out_size, void* d_ws,
                              size_t ws_size, hipStream_t stream) {
  const float* x = (const float*)d_in[0];
  const float* u = (const float*)d_in[1];
  const float* W = (const float*)d_in[2];
  const float* bias = (const float*)d_in[3];
  const float* cb = (const float*)d_in[4];
  float* out = (float*)d_out;

  // ws layout: [0,40960) counts | [40960,41088) entropy partials |
  // [65536, +5242880) top2 partials | wt_h | wt_l   (total ~7.93 MB)
  int* counts = (int*)d_ws;
  float* epart = (float*)((char*)d_ws + 40960);
  float4* partial = (float4*)((char*)d_ws + 65536);
  u16* wth = (u16*)((char*)d_ws + 65536 + (size_t)Msz * 10 * 16);
  u16* wtl = wth + (size_t)Fsz * Esz;

  hipMemsetAsync(d_ws, 0, 40960, stream);
  k_prep<<<Fsz, 256, 0, stream>>>(W, wth, wtl);
  k_gemm<<<dim3(Fsz / BN, Msz / BM), 256, 0, stream>>>(x, u, bias, wth, wtl,
                                                       partial);
  k_select<<<Msz / 256, 256, 0, stream>>>(partial, x, W, bias, u, cb, out,
                                          counts);
  k_entropy<<<Bsz * Gsz, 64, 0, stream>>>(counts, epart);
  k_final<<<1, 64, 0, stream>>>(epart, out + (size_t)Msz * Esz);
}